// Round 4
// baseline (285.115 us; speedup 1.0000x reference)
//
#include <hip/hip_runtime.h>
#include <math.h>

#define BTOT 131072
#define NBK 3
#define SS 16
#define NA 9
#define BAD 25      // SS+NA
#define STR 28      // padded row stride in the fp32 weight image
#define VD 128
#define CM 10
#define OUTD 51     // NBK*SS + 3
#define EPS 1e-8f

// ---- fp32 folded-weight image (float offsets in ws) ----
#define O_GQK  0        // 25 x 28  full Wq^T Wk
#define O_GQQ  700      // 25 x 28  lower-tri (off-diag x2) of Wq^T Wq
#define O_GKK  1400     // 25 x 28  lower-tri (off-diag x2) of Wk^T Wk
#define O_V1   2100     // 28: Wq^T bk
#define O_V2   2128     // 28: Wk^T bq
#define O_VQ   2156     // 28: Wq^T bq
#define O_VK   2184     // 28: Wk^T bk
#define O_C    2212     // c0, cq, ck, pad
#define O_M    2216     // (dead region)
#define O_B2   7976     // 16
#define O_WC1  7992     // 10 x 84
#define O_BC1  8832     // 12
#define O_WC2  8844     // 3 x 12
#define O_BC2  8880     // 4
#define LDS_F  8884
// ---- bf16 MFMA-packed B-fragments appended after the fp32 image ----
#define O_PKM  LDS_F          // 4096 ushorts = 2048 floats
#define O_PKW2 (LDS_F + 2048) // 2048 ushorts = 1024 floats
#define PKM_N  4096
#define PKW2_N 2048

#define NDOT  (O_M + PKM_N)   // 2216 fp32 dots + 4096 pkM dots
#define NCOPY (16 + 840 + 12 + 36 + 4 + PKW2_N)

typedef __attribute__((ext_vector_type(8))) short short8;
typedef __attribute__((ext_vector_type(4))) float floatx4;

__device__ __forceinline__ float fast_sigmoid(float x) {
    return __builtin_amdgcn_rcpf(1.0f + __expf(-x));
}

__device__ __forceinline__ unsigned short f2bf(float f) {
    unsigned int u = __float_as_uint(f);
    u += 0x7FFFu + ((u >> 16) & 1u);   // round-to-nearest-even
    return (unsigned short)(u >> 16);
}

// ---------------- prep: wave-per-output 128-length dot products ----------------
__global__ __launch_bounds__(256) void prep_dots(
    const float* __restrict__ Wq, const float* __restrict__ bq,
    const float* __restrict__ Wk, const float* __restrict__ bk,
    const float* __restrict__ Wv, const float* __restrict__ bv,
    const float* __restrict__ W1, const float* __restrict__ b1,
    float* __restrict__ ws) {
    int lane = threadIdx.x & 63;
    int gidx = blockIdx.x * 4 + (threadIdx.x >> 6);
    if (gidx >= NDOT) return;

    const float* pa = bq;  const float* pb = bk;   // safe defaults
    int sa = 1, sb = 1;
    float scale = 1.0f, bias = 0.0f;
    bool zero = false;
    bool isbf = false; int bfpos = 0;

    if (gidx < O_M) {
        int idx = gidx;
        if (idx < O_GQQ) {
            int e = idx / STR, f = idx % STR;
            if (f < BAD) { pa = Wq + e; sa = BAD; pb = Wk + f; sb = BAD; }
            else zero = true;
        } else if (idx < O_GKK) {
            int j = idx - O_GQQ; int e = j / STR, f = j % STR;
            if (f < BAD && f <= e) { pa = Wq + e; sa = BAD; pb = Wq + f; sb = BAD; scale = (f == e) ? 1.0f : 2.0f; }
            else zero = true;
        } else if (idx < O_V1) {
            int j = idx - O_GKK; int e = j / STR, f = j % STR;
            if (f < BAD && f <= e) { pa = Wk + e; sa = BAD; pb = Wk + f; sb = BAD; scale = (f == e) ? 1.0f : 2.0f; }
            else zero = true;
        } else if (idx < O_V2) {
            int e = idx - O_V1;
            if (e < BAD) { pa = Wq + e; sa = BAD; pb = bk; }
            else zero = true;
        } else if (idx < O_VQ) {
            int e = idx - O_V2;
            if (e < BAD) { pa = Wk + e; sa = BAD; pb = bq; }
            else zero = true;
        } else if (idx < O_VK) {
            int e = idx - O_VQ;
            if (e < BAD) { pa = Wq + e; sa = BAD; pb = bq; }
            else zero = true;
        } else if (idx < O_C) {
            int e = idx - O_VK;
            if (e < BAD) { pa = Wk + e; sa = BAD; pb = bk; }
            else zero = true;
        } else {
            int j = idx - O_C;
            if (j == 0)      { pa = bq; pb = bk; }
            else if (j == 1) { pa = bq; pb = bq; }
            else if (j == 2) { pa = bk; pb = bk; }
            else zero = true;
        }
    } else {
        // pkM B-frag: B[k][n], n = tile*16 + (l&15), k = (l>>4)*8 + j
        int p = gidx - O_M;
        isbf = true; bfpos = p;
        int l2 = (p >> 3) & 63, j = p & 7;
        int n = (p >> 9) * 16 + (l2 & 15);
        int k = ((l2 >> 4) << 3) + j;
        if (k < BAD)       { pa = W1 + n * VD; pb = Wv + k; sb = BAD; scale = 2.0f; }
        else if (k == BAD) { pa = W1 + n * VD; pb = bv; scale = 2.0f; bias = 2.0f * b1[n]; }
        else zero = true;
    }

    float s = 0.0f;
    if (!zero)
        s = pa[sa * lane] * pb[sb * lane] + pa[sa * (lane + 64)] * pb[sb * (lane + 64)];
    #pragma unroll
    for (int off = 1; off < 64; off <<= 1) s += __shfl_xor(s, off);
    float val = zero ? 0.0f : (s * scale + bias);
    if (lane == 0) {
        if (isbf) ((unsigned short*)(ws + O_PKM))[bfpos] = f2bf(val);
        else ws[gidx] = val;
    }
}

__global__ __launch_bounds__(256) void prep_copy(
    const float* __restrict__ W2, const float* __restrict__ b2,
    const float* __restrict__ Wc1, const float* __restrict__ bc1,
    const float* __restrict__ Wc2, const float* __restrict__ bc2,
    float* __restrict__ ws) {
    int c = blockIdx.x * 256 + threadIdx.x;
    if (c >= NCOPY) return;
    if (c < 16) { ws[O_B2 + c] = b2[c]; return; }
    c -= 16;
    if (c < 840) {
        int m = c / 84, r = c % 84, i = r / STR, f = r % STR;
        ws[O_WC1 + c] = (f < BAD) ? Wc1[m * (NBK * BAD) + i * BAD + f] : 0.0f;
        return;
    }
    c -= 840;
    if (c < 12) { ws[O_BC1 + c] = (c < CM) ? bc1[c] : 0.0f; return; }
    c -= 12;
    if (c < 36) { int o = c / 12, mm = c % 12; ws[O_WC2 + c] = (mm < CM) ? Wc2[o * CM + mm] : 0.0f; return; }
    c -= 36;
    if (c < 4) { ws[O_BC2 + c] = (c < 3) ? bc2[c] : 0.0f; return; }
    c -= 4;
    // pkW2 B-frag: B[k][o], o = l&15, k = kt*32 + (l>>4)*8 + j
    int kt = c >> 9, l = (c >> 3) & 63, j = c & 7;
    int o = l & 15;
    int k = kt * 32 + ((l >> 4) << 3) + j;
    ((unsigned short*)(ws + O_PKW2))[c] = f2bf(W2[o * VD + k]);
}

// ---------------- fused main kernel: WAVE-SPECIALIZED, 128-thread blocks ----
// Block = 128 threads = 2 waves over 64 elements. Wave 0: phase 1 (attention
// scores + conf MLP, work-efficient fp32 math) -> a_tilde bf16 to LDS.
// Wave 1: phase 2 (swapped-MFMA GEMM1 -> tanh -> register-bpermute -> GEMM2),
// 12 tiles, B-fragments prefetched BEFORE the barrier.
// 4096 waves total (2x the 1-thread-per-element supply) with zero duplicated
// math. NO register-capping launch bound: round 3 proved capping below
// phase-1's ~144-VGPR working set spills to scratch (hbm_bytes 4.7e7->3.8e8).
__global__ __launch_bounds__(128) void main_kernel(
    const float* __restrict__ states, const float* __restrict__ action,
    const int* __restrict__ block_id,
    const float* __restrict__ ws, float* __restrict__ out) {
    __shared__ __align__(16) unsigned short At[192 * 40];   // 15360 B

    int t = threadIdx.x;
    int lane = t & 63;

    // ---- phase-2 wave: prefetch fragments before the barrier ----
    short8 pm[8]; short8 pw[4];
    float b2v = 0.0f;
    if (t >= 64) {
        const short8* pkM = (const short8*)(ws + O_PKM);
        const short8* pkW2 = (const short8*)(ws + O_PKW2);
        #pragma unroll
        for (int nt = 0; nt < 8; ++nt) pm[nt] = pkM[nt * 64 + lane];
        #pragma unroll
        for (int kt = 0; kt < 4; ++kt) pw[kt] = pkW2[kt * 64 + lane];
        b2v = ws[O_B2 + (lane & 15)];
    }

    if (t < 64) {
        // ================= phase 1 (1 thread = 1 element) =================
        long elem = (long)blockIdx.x * 64 + t;
        const float* st = states + elem * (NBK * SS);
        const float* ac = action + elem * NA;
        const int* bid = block_id + elem * NBK;

        // ---- build ba[3][25] (all indices compile-time) ----
        float ba[NBK * BAD];
        #pragma unroll
        for (int i = 0; i < NBK; ++i) {
            const float4* s4 = (const float4*)(st + i * SS);
            #pragma unroll
            for (int w4 = 0; w4 < 4; ++w4) {
                float4 v = s4[w4];
                ba[i * BAD + w4 * 4 + 0] = v.x;
                ba[i * BAD + w4 * 4 + 1] = v.y;
                ba[i * BAD + w4 * 4 + 2] = v.z;
                ba[i * BAD + w4 * 4 + 3] = v.w;
            }
            bool sel = (bid[i] == 1);
            #pragma unroll
            for (int c = 0; c < NA; ++c)
                ba[i * BAD + SS + c] = sel ? ac[c] : -1.0f;
        }

        // ---- confidence MLP ----
        {
            float hm[CM];
            #pragma unroll
            for (int m = 0; m < CM; ++m) {
                float s = ws[O_BC1 + m];
                #pragma unroll
                for (int i = 0; i < NBK; ++i)
                    #pragma unroll
                    for (int f = 0; f < BAD; ++f)
                        s += ws[O_WC1 + m * 84 + i * STR + f] * ba[i * BAD + f];
                hm[m] = fast_sigmoid(s);
            }
            float* op = out + elem * OUTD;
            #pragma unroll
            for (int o = 0; o < 3; ++o) {
                float s = ws[O_BC2 + o];
                #pragma unroll
                for (int m = 0; m < CM; ++m) s += ws[O_WC2 + o * 12 + m] * hm[m];
                op[48 + o] = fast_sigmoid(s);
            }
        }

        // ---- linear score terms ----
        float s1[NBK], s2[NBK], dq[NBK], dk[NBK];
        #pragma unroll
        for (int p = 0; p < NBK; ++p) {
            float a1 = 0.f, a2 = 0.f, aq = 0.f, ak = 0.f;
            #pragma unroll
            for (int e = 0; e < BAD; ++e) {
                float b = ba[p * BAD + e];
                a1 += ws[O_V1 + e] * b;
                a2 += ws[O_V2 + e] * b;
                aq += ws[O_VQ + e] * b;
                ak += ws[O_VK + e] * b;
            }
            s1[p] = a1; s2[p] = a2; dq[p] = aq; dk[p] = ak;
        }
        float c0 = ws[O_C + 0], cq = ws[O_C + 1], ck = ws[O_C + 2];

        // ---- bilinear numerators ----
        float num[NBK][NBK] = {{0.f,0.f,0.f},{0.f,0.f,0.f},{0.f,0.f,0.f}};
        #pragma unroll
        for (int e = 0; e < BAD; ++e) {
            float t0 = 0.f, t1 = 0.f, t2 = 0.f;
            #pragma unroll
            for (int f = 0; f < BAD; ++f) {
                float g = ws[O_GQK + e * STR + f];
                t0 += g * ba[0 * BAD + f];
                t1 += g * ba[1 * BAD + f];
                t2 += g * ba[2 * BAD + f];
            }
            #pragma unroll
            for (int i = 0; i < NBK; ++i) {
                float be = ba[i * BAD + e];
                num[i][0] += be * t0;
                num[i][1] += be * t1;
                num[i][2] += be * t2;
            }
        }

        // ---- quadratic forms via scaled lower triangles ----
        float qn2[NBK] = {0.f, 0.f, 0.f}, kn2[NBK] = {0.f, 0.f, 0.f};
        #pragma unroll
        for (int e = 0; e < BAD; ++e) {
            float pq0 = 0.f, pq1 = 0.f, pq2 = 0.f;
            float pk0 = 0.f, pk1 = 0.f, pk2 = 0.f;
            #pragma unroll
            for (int f = 0; f <= e; ++f) {
                float gq = ws[O_GQQ + e * STR + f];
                float gk = ws[O_GKK + e * STR + f];
                float b0 = ba[0 * BAD + f], b1v = ba[1 * BAD + f], b2vv = ba[2 * BAD + f];
                pq0 += gq * b0; pq1 += gq * b1v; pq2 += gq * b2vv;
                pk0 += gk * b0; pk1 += gk * b1v; pk2 += gk * b2vv;
            }
            qn2[0] += ba[0 * BAD + e] * pq0;
            qn2[1] += ba[1 * BAD + e] * pq1;
            qn2[2] += ba[2 * BAD + e] * pq2;
            kn2[0] += ba[0 * BAD + e] * pk0;
            kn2[1] += ba[1 * BAD + e] * pk1;
            kn2[2] += ba[2 * BAD + e] * pk2;
        }
        #pragma unroll
        for (int p = 0; p < NBK; ++p) {
            qn2[p] += 2.0f * dq[p] + cq;
            kn2[p] += 2.0f * dk[p] + ck;
        }

        // ---- softmax over j ----
        float att[NBK][NBK];
        {
            float kn[NBK];
            #pragma unroll
            for (int j = 0; j < NBK; ++j) kn[j] = __builtin_amdgcn_sqrtf(fmaxf(kn2[j], 0.0f));
            #pragma unroll
            for (int i = 0; i < NBK; ++i) {
                float qn = __builtin_amdgcn_sqrtf(fmaxf(qn2[i], 0.0f));
                float dv[NBK];
                #pragma unroll
                for (int j = 0; j < NBK; ++j)
                    dv[j] = (num[i][j] + s1[i] + s2[j] + c0) *
                            __builtin_amdgcn_rcpf(fmaxf(qn * kn[j], EPS));
                float mx = fmaxf(dv[0], fmaxf(dv[1], dv[2]));
                float e0 = __expf(dv[0] - mx);
                float e1 = __expf(dv[1] - mx);
                float e2 = __expf(dv[2] - mx);
                float inv = __builtin_amdgcn_rcpf(e0 + e1 + e2);
                att[i][0] = e0 * inv;
                att[i][1] = e1 * inv;
                att[i][2] = e2 * inv;
            }
        }

        // ---- a_tilde (in place) ----
        #pragma unroll
        for (int e = 0; e < BAD; ++e) {
            float b0 = ba[0 * BAD + e], b1v = ba[1 * BAD + e], b2vv = ba[2 * BAD + e];
            ba[0 * BAD + e] = att[0][0] * b0 + att[0][1] * b1v + att[0][2] * b2vv;
            ba[1 * BAD + e] = att[1][0] * b0 + att[1][1] * b1v + att[1][2] * b2vv;
            ba[2 * BAD + e] = att[2][0] * b0 + att[2][1] * b1v + att[2][2] * b2vv;
        }

        // ---- write a_tilde rows to LDS as bf16 (col 25 = 1.0, 26..31 = 0) ----
        #pragma unroll
        for (int i = 0; i < NBK; ++i) {
            unsigned int* dst = (unsigned int*)&At[(t * 3 + i) * 40];
            #pragma unroll
            for (int pr = 0; pr < 12; ++pr)
                dst[pr] = (unsigned int)f2bf(ba[i * BAD + 2 * pr]) |
                          ((unsigned int)f2bf(ba[i * BAD + 2 * pr + 1]) << 16);
            dst[12] = (unsigned int)f2bf(ba[i * BAD + 24]) | (0x3F80u << 16);
            dst[13] = 0u; dst[14] = 0u; dst[15] = 0u;
        }
    }

    __syncthreads();

    if (t >= 64) {
        // ================= phase 2: MFMA (12 tiles, one wave) =================
        int m = lane & 15, q = lane >> 4;
        long blockbase = (long)blockIdx.x * 64;
        int addrA = ((q & 1) ? (m + 32) : m) << 2;
        int addrB = addrA + 64;
        bool hiSel = (q >= 2);            // selects nt_s = 2kt + (q>>1)

        for (int tile = 0; tile < 12; ++tile) {
            short8 af = *(const short8*)&At[(tile * 16 + m) * 40 + q * 8];
            // GEMM1 swapped: lane (m,q) reg (nt,rr) = P[tile*16+m][nt*16+q*4+rr]
            floatx4 accT[8];
            #pragma unroll
            for (int nt = 0; nt < 8; ++nt) {
                floatx4 z = {0.f, 0.f, 0.f, 0.f};
                accT[nt] = __builtin_amdgcn_mfma_f32_16x16x32_bf16(pm[nt], af, z, 0, 0, 0);
            }
            // tanh + pack adjacent-col pairs into bf16 dwords
            unsigned int pk[8][2];
            #pragma unroll
            for (int nt = 0; nt < 8; ++nt) {
                float x0 = fmaf(-2.0f, __builtin_amdgcn_rcpf(1.0f + __expf(accT[nt][0])), 1.0f);
                float x1 = fmaf(-2.0f, __builtin_amdgcn_rcpf(1.0f + __expf(accT[nt][1])), 1.0f);
                float x2 = fmaf(-2.0f, __builtin_amdgcn_rcpf(1.0f + __expf(accT[nt][2])), 1.0f);
                float x3 = fmaf(-2.0f, __builtin_amdgcn_rcpf(1.0f + __expf(accT[nt][3])), 1.0f);
                asm("v_cvt_pk_bf16_f32 %0, %1, %2" : "=v"(pk[nt][0]) : "v"(x0), "v"(x1));
                asm("v_cvt_pk_bf16_f32 %0, %1, %2" : "=v"(pk[nt][1]) : "v"(x2), "v"(x3));
            }
            // GEMM2: A2[m][kt*32+q*8+j] gathered via register bpermute.
            floatx4 acc2 = {0.f, 0.f, 0.f, 0.f};
            #pragma unroll
            for (int kt = 0; kt < 4; ++kt) {
                int lo0 = __builtin_amdgcn_ds_bpermute(addrA, (int)pk[2 * kt][0]);
                int hi0 = __builtin_amdgcn_ds_bpermute(addrA, (int)pk[2 * kt + 1][0]);
                int lo1 = __builtin_amdgcn_ds_bpermute(addrA, (int)pk[2 * kt][1]);
                int hi1 = __builtin_amdgcn_ds_bpermute(addrA, (int)pk[2 * kt + 1][1]);
                int lo2 = __builtin_amdgcn_ds_bpermute(addrB, (int)pk[2 * kt][0]);
                int hi2 = __builtin_amdgcn_ds_bpermute(addrB, (int)pk[2 * kt + 1][0]);
                int lo3 = __builtin_amdgcn_ds_bpermute(addrB, (int)pk[2 * kt][1]);
                int hi3 = __builtin_amdgcn_ds_bpermute(addrB, (int)pk[2 * kt + 1][1]);
                union { unsigned int u[4]; short8 s; } a2u;
                a2u.u[0] = (unsigned int)(hiSel ? hi0 : lo0);
                a2u.u[1] = (unsigned int)(hiSel ? hi1 : lo1);
                a2u.u[2] = (unsigned int)(hiSel ? hi2 : lo2);
                a2u.u[3] = (unsigned int)(hiSel ? hi3 : lo3);
                acc2 = __builtin_amdgcn_mfma_f32_16x16x32_bf16(a2u.s, pw[kt], acc2, 0, 0, 0);
            }
            // epilogue: + states + b2, store (D2: row=q*4+rr, col o=m)
            #pragma unroll
            for (int rr = 0; rr < 4; ++rr) {
                int lrow = tile * 16 + q * 4 + rr;     // 0..191
                int et = lrow / 3, i = lrow - et * 3;
                long ge = blockbase + et;
                float base = states[ge * 48 + i * 16 + m];
                out[ge * OUTD + i * 16 + m] = acc2[rr] + base + b2v;
            }
        }
    }
}

extern "C" void kernel_launch(void* const* d_in, const int* in_sizes, int n_in,
                              void* d_out, int out_size, void* d_ws, size_t ws_size,
                              hipStream_t stream) {
    const float* states = (const float*)d_in[0];
    const float* action = (const float*)d_in[1];
    const int* block_id = (const int*)d_in[2];
    const float* Wq = (const float*)d_in[3];
    const float* bq = (const float*)d_in[4];
    const float* Wk = (const float*)d_in[5];
    const float* bk = (const float*)d_in[6];
    const float* Wv = (const float*)d_in[7];
    const float* bv = (const float*)d_in[8];
    const float* W1 = (const float*)d_in[9];
    const float* b1 = (const float*)d_in[10];
    const float* W2 = (const float*)d_in[11];
    const float* b2 = (const float*)d_in[12];
    const float* Wc1 = (const float*)d_in[13];
    const float* bc1 = (const float*)d_in[14];
    const float* Wc2 = (const float*)d_in[15];
    const float* bc2 = (const float*)d_in[16];
    float* out = (float*)d_out;
    float* ws = (float*)d_ws;

    hipLaunchKernelGGL(prep_dots, dim3((NDOT + 3) / 4), dim3(256), 0, stream,
                       Wq, bq, Wk, bk, Wv, bv, W1, b1, ws);
    hipLaunchKernelGGL(prep_copy, dim3((NCOPY + 255) / 256), dim3(256), 0, stream,
                       W2, b2, Wc1, bc1, Wc2, bc2, ws);
    hipLaunchKernelGGL(main_kernel, dim3(BTOT / 64), dim3(128), 0, stream,
                       states, action, block_id, ws, out);
}

// Round 5
// 167.793 us; speedup vs baseline: 1.6992x; 1.6992x over previous
//
#include <hip/hip_runtime.h>
#include <math.h>

#define BTOT 131072
#define NBK 3
#define SS 16
#define NA 9
#define BAD 25      // SS+NA
#define STR 28      // padded row stride in the fp32 weight image
#define VD 128
#define CM 10
#define OUTD 51     // NBK*SS + 3
#define EPS 1e-8f

// ---- fp32 folded-weight image (float offsets in ws) ----
#define O_GQK  0        // 25 x 28  full Wq^T Wk
#define O_GQQ  700      // 25 x 28  lower-tri (off-diag x2) of Wq^T Wq
#define O_GKK  1400     // 25 x 28  lower-tri (off-diag x2) of Wk^T Wk
#define O_V1   2100     // 28: Wq^T bk
#define O_V2   2128     // 28: Wk^T bq
#define O_VQ   2156     // 28: Wq^T bq
#define O_VK   2184     // 28: Wk^T bk
#define O_C    2212     // c0, cq, ck, pad
#define O_M    2216     // (dead region)
#define O_B2   7976     // 16
#define O_WC1  7992     // 10 x 84
#define O_BC1  8832     // 12
#define O_WC2  8844     // 3 x 12
#define O_BC2  8880     // 4
#define LDS_F  8884
// ---- bf16 MFMA-packed B-fragments appended after the fp32 image ----
#define O_PKM  LDS_F          // 4096 ushorts = 2048 floats
#define O_PKW2 (LDS_F + 2048) // 2048 ushorts = 1024 floats
#define PKM_N  4096
#define PKW2_N 2048

#define NDOT  (O_M + PKM_N)   // 2216 fp32 dots + 4096 pkM dots
#define NCOPY (16 + 840 + 12 + 36 + 4 + PKW2_N)

typedef __attribute__((ext_vector_type(8))) short short8;
typedef __attribute__((ext_vector_type(4))) float floatx4;

__device__ __forceinline__ float fast_sigmoid(float x) {
    return __builtin_amdgcn_rcpf(1.0f + __expf(-x));
}

__device__ __forceinline__ unsigned short f2bf(float f) {
    unsigned int u = __float_as_uint(f);
    u += 0x7FFFu + ((u >> 16) & 1u);   // round-to-nearest-even
    return (unsigned short)(u >> 16);
}

// ---------------- prep: wave-per-output 128-length dot products ----------------
__global__ __launch_bounds__(256) void prep_dots(
    const float* __restrict__ Wq, const float* __restrict__ bq,
    const float* __restrict__ Wk, const float* __restrict__ bk,
    const float* __restrict__ Wv, const float* __restrict__ bv,
    const float* __restrict__ W1, const float* __restrict__ b1,
    float* __restrict__ ws) {
    int lane = threadIdx.x & 63;
    int gidx = blockIdx.x * 4 + (threadIdx.x >> 6);
    if (gidx >= NDOT) return;

    const float* pa = bq;  const float* pb = bk;   // safe defaults
    int sa = 1, sb = 1;
    float scale = 1.0f, bias = 0.0f;
    bool zero = false;
    bool isbf = false; int bfpos = 0;

    if (gidx < O_M) {
        int idx = gidx;
        if (idx < O_GQQ) {
            int e = idx / STR, f = idx % STR;
            if (f < BAD) { pa = Wq + e; sa = BAD; pb = Wk + f; sb = BAD; }
            else zero = true;
        } else if (idx < O_GKK) {
            int j = idx - O_GQQ; int e = j / STR, f = j % STR;
            if (f < BAD && f <= e) { pa = Wq + e; sa = BAD; pb = Wq + f; sb = BAD; scale = (f == e) ? 1.0f : 2.0f; }
            else zero = true;
        } else if (idx < O_V1) {
            int j = idx - O_GKK; int e = j / STR, f = j % STR;
            if (f < BAD && f <= e) { pa = Wk + e; sa = BAD; pb = Wk + f; sb = BAD; scale = (f == e) ? 1.0f : 2.0f; }
            else zero = true;
        } else if (idx < O_V2) {
            int e = idx - O_V1;
            if (e < BAD) { pa = Wq + e; sa = BAD; pb = bk; }
            else zero = true;
        } else if (idx < O_VQ) {
            int e = idx - O_V2;
            if (e < BAD) { pa = Wk + e; sa = BAD; pb = bq; }
            else zero = true;
        } else if (idx < O_VK) {
            int e = idx - O_VQ;
            if (e < BAD) { pa = Wq + e; sa = BAD; pb = bq; }
            else zero = true;
        } else if (idx < O_C) {
            int e = idx - O_VK;
            if (e < BAD) { pa = Wk + e; sa = BAD; pb = bk; }
            else zero = true;
        } else {
            int j = idx - O_C;
            if (j == 0)      { pa = bq; pb = bk; }
            else if (j == 1) { pa = bq; pb = bq; }
            else if (j == 2) { pa = bk; pb = bk; }
            else zero = true;
        }
    } else {
        // pkM B-frag: B[k][n], n = tile*16 + (l&15), k = (l>>4)*8 + j
        int p = gidx - O_M;
        isbf = true; bfpos = p;
        int l2 = (p >> 3) & 63, j = p & 7;
        int n = (p >> 9) * 16 + (l2 & 15);
        int k = ((l2 >> 4) << 3) + j;
        if (k < BAD)       { pa = W1 + n * VD; pb = Wv + k; sb = BAD; scale = 2.0f; }
        else if (k == BAD) { pa = W1 + n * VD; pb = bv; scale = 2.0f; bias = 2.0f * b1[n]; }
        else zero = true;
    }

    float s = 0.0f;
    if (!zero)
        s = pa[sa * lane] * pb[sb * lane] + pa[sa * (lane + 64)] * pb[sb * (lane + 64)];
    #pragma unroll
    for (int off = 1; off < 64; off <<= 1) s += __shfl_xor(s, off);
    float val = zero ? 0.0f : (s * scale + bias);
    if (lane == 0) {
        if (isbf) ((unsigned short*)(ws + O_PKM))[bfpos] = f2bf(val);
        else ws[gidx] = val;
    }
}

__global__ __launch_bounds__(256) void prep_copy(
    const float* __restrict__ W2, const float* __restrict__ b2,
    const float* __restrict__ Wc1, const float* __restrict__ bc1,
    const float* __restrict__ Wc2, const float* __restrict__ bc2,
    float* __restrict__ ws) {
    int c = blockIdx.x * 256 + threadIdx.x;
    if (c >= NCOPY) return;
    if (c < 16) { ws[O_B2 + c] = b2[c]; return; }
    c -= 16;
    if (c < 840) {
        int m = c / 84, r = c % 84, i = r / STR, f = r % STR;
        ws[O_WC1 + c] = (f < BAD) ? Wc1[m * (NBK * BAD) + i * BAD + f] : 0.0f;
        return;
    }
    c -= 840;
    if (c < 12) { ws[O_BC1 + c] = (c < CM) ? bc1[c] : 0.0f; return; }
    c -= 12;
    if (c < 36) { int o = c / 12, mm = c % 12; ws[O_WC2 + c] = (mm < CM) ? Wc2[o * CM + mm] : 0.0f; return; }
    c -= 36;
    if (c < 4) { ws[O_BC2 + c] = (c < 3) ? bc2[c] : 0.0f; return; }
    c -= 4;
    // pkW2 B-frag: B[k][o], o = l&15, k = kt*32 + (l>>4)*8 + j
    int kt = c >> 9, l = (c >> 3) & 63, j = c & 7;
    int o = l & 15;
    int k = kt * 32 + ((l >> 4) << 3) + j;
    ((unsigned short*)(ws + O_PKW2))[c] = f2bf(W2[o * VD + k]);
}

// ---------------- fused main kernel: LANE-PAIR SPLIT phase 1 ----------------
// 2 lanes per element (h = t&1). Phase-1 heavy math is SPLIT (not duplicated):
//   h=0: GQQ triangle (qn2), s1/dq, even-e num rows, conf m0-4, a_tilde e0-11
//   h=1: GKK triangle (kn2), s2/dk, odd-e num rows,  conf m5-9, a_tilde e12-24
// Cross-half exchange: ~20 shfl_xor(.,1) (DPP). Only ba-build and the 3x3
// softmax are duplicated (~5% of work). 1024 blocks x 4 waves = 4096 waves at
// ~0.56x work each (vs round-1's 2048 waves) -> latency hiding at equal total
// work. Phase 2: round-1 verified MFMA path, 6 tiles/wave, wave-private At.
__global__ __launch_bounds__(256) void main_kernel(
    const float* __restrict__ states, const float* __restrict__ action,
    const int* __restrict__ block_id,
    const float* __restrict__ ws, float* __restrict__ out) {
    __shared__ __align__(16) unsigned short At[384 * 40];   // 30720 B

    int t = threadIdx.x;
    int lane = t & 63;
    int h = t & 1;
    int le = t >> 1;                        // local element 0..127
    long elem = (long)blockIdx.x * 128 + le;

    const float* st = states + elem * (NBK * SS);
    const float* ac = action + elem * NA;
    const int* bid = block_id + elem * NBK;

    // ---- build ba[3][25] (both lanes of the pair; compile-time indices) ----
    float ba[NBK * BAD];
    #pragma unroll
    for (int i = 0; i < NBK; ++i) {
        const float4* s4 = (const float4*)(st + i * SS);
        #pragma unroll
        for (int w4 = 0; w4 < 4; ++w4) {
            float4 v = s4[w4];
            ba[i * BAD + w4 * 4 + 0] = v.x;
            ba[i * BAD + w4 * 4 + 1] = v.y;
            ba[i * BAD + w4 * 4 + 2] = v.z;
            ba[i * BAD + w4 * 4 + 3] = v.w;
        }
        bool sel = (bid[i] == 1);
        #pragma unroll
        for (int c = 0; c < NA; ++c)
            ba[i * BAD + SS + c] = sel ? ac[c] : -1.0f;
    }

    // ---- confidence MLP: h computes its 5 hidden units ----
    {
        const float* wc = ws + O_WC1 + h * 5 * 84;   // per-lane base
        const float* bc = ws + O_BC1 + h * 5;
        float hp[5];
        #pragma unroll
        for (int k = 0; k < 5; ++k) {
            float s = bc[k];
            #pragma unroll
            for (int i = 0; i < NBK; ++i)
                #pragma unroll
                for (int f = 0; f < BAD; ++f)
                    s += wc[k * 84 + i * STR + f] * ba[i * BAD + f];
            hp[k] = fast_sigmoid(s);
        }
        float op5[5];
        #pragma unroll
        for (int k = 0; k < 5; ++k) op5[k] = __shfl_xor(hp[k], 1);
        if (h == 0) {
            // hm = [hp 0..4, op5 0..4]
            float* op = out + elem * OUTD;
            #pragma unroll
            for (int o = 0; o < 3; ++o) {
                float s = ws[O_BC2 + o];
                #pragma unroll
                for (int m = 0; m < 5; ++m) s += ws[O_WC2 + o * 12 + m] * hp[m];
                #pragma unroll
                for (int m = 0; m < 5; ++m) s += ws[O_WC2 + o * 12 + 5 + m] * op5[m];
                op[48 + o] = fast_sigmoid(s);
            }
        }
    }

    // ---- linear terms: h=0 -> s1(V1), dq(VQ); h=1 -> s2(V2), dk(VK) ----
    float sl[NBK], dd[NBK];
    {
        const float* vA = ws + (h ? O_V2 : O_V1);
        const float* vB = ws + (h ? O_VK : O_VQ);
        #pragma unroll
        for (int p = 0; p < NBK; ++p) {
            float sA = 0.f, sB = 0.f;
            #pragma unroll
            for (int e = 0; e < BAD; ++e) {
                float b = ba[p * BAD + e];
                sA = fmaf(vA[e], b, sA);
                sB = fmaf(vB[e], b, sB);
            }
            sl[p] = sA; dd[p] = sB;
        }
    }

    // ---- bilinear numerators: interleaved e split (h=0 even, h=1 odd) ----
    float nm[NBK][NBK] = {{0.f,0.f,0.f},{0.f,0.f,0.f},{0.f,0.f,0.f}};
    {
        const float* gq = ws + O_GQK + h * STR;   // per-lane base (row h)
        #pragma unroll
        for (int i13 = 0; i13 < 13; ++i13) {
            // e = 2*i13 + h; for i13==12: ec=24 for both lanes, h=1 zeroed
            const float* grow = (i13 == 12) ? (ws + O_GQK + 24 * STR)
                                            : (gq + i13 * 2 * STR);
            float t0 = 0.f, t1 = 0.f, t2 = 0.f;
            #pragma unroll
            for (int f = 0; f < BAD; ++f) {
                float g = grow[f];
                t0 = fmaf(g, ba[0 * BAD + f], t0);
                t1 = fmaf(g, ba[1 * BAD + f], t1);
                t2 = fmaf(g, ba[2 * BAD + f], t2);
            }
            float zs = (i13 == 12) ? (1.0f - (float)h) : 1.0f;
            #pragma unroll
            for (int i = 0; i < NBK; ++i) {
                float be;
                if (i13 == 12) be = ba[i * BAD + 24] * zs;
                else {
                    // e = 2*i13 + h : runtime index only through ba -> select
                    float b_even = ba[i * BAD + 2 * i13];
                    float b_odd  = ba[i * BAD + 2 * i13 + 1];
                    be = h ? b_odd : b_even;
                }
                nm[i][0] = fmaf(be, t0, nm[i][0]);
                nm[i][1] = fmaf(be, t1, nm[i][1]);
                nm[i][2] = fmaf(be, t2, nm[i][2]);
            }
        }
        // combine halves
        #pragma unroll
        for (int i = 0; i < NBK; ++i)
            #pragma unroll
            for (int j = 0; j < NBK; ++j)
                nm[i][j] += __shfl_xor(nm[i][j], 1);
    }

    // ---- quadratic form: h=0 -> GQQ (qn2), h=1 -> GKK (kn2) ----
    float sn2[NBK] = {0.f, 0.f, 0.f};
    {
        const float* gt = ws + (h ? O_GKK : O_GQQ);   // per-lane base
        #pragma unroll
        for (int e = 0; e < BAD; ++e) {
            float p0 = 0.f, p1 = 0.f, p2 = 0.f;
            #pragma unroll
            for (int f = 0; f <= e; ++f) {
                float g = gt[e * STR + f];
                p0 = fmaf(g, ba[0 * BAD + f], p0);
                p1 = fmaf(g, ba[1 * BAD + f], p1);
                p2 = fmaf(g, ba[2 * BAD + f], p2);
            }
            sn2[0] = fmaf(ba[0 * BAD + e], p0, sn2[0]);
            sn2[1] = fmaf(ba[1 * BAD + e], p1, sn2[1]);
            sn2[2] = fmaf(ba[2 * BAD + e], p2, sn2[2]);
        }
    }
    float c0 = ws[O_C + 0];
    float cc = ws[O_C + 1 + h];              // cq (h=0) or ck (h=1)
    float rn[NBK];
    #pragma unroll
    for (int p = 0; p < NBK; ++p) {
        sn2[p] += 2.0f * dd[p] + cc;
        rn[p] = __builtin_amdgcn_sqrtf(fmaxf(sn2[p], 0.0f));
    }

    // ---- exchange row norms and linear sums across the pair ----
    float orn[NBK], osl[NBK];
    #pragma unroll
    for (int p = 0; p < NBK; ++p) {
        orn[p] = __shfl_xor(rn[p], 1);
        osl[p] = __shfl_xor(sl[p], 1);
    }
    float s1v[NBK], s2v[NBK], qv[NBK], kv[NBK];
    #pragma unroll
    for (int p = 0; p < NBK; ++p) {
        s1v[p] = h ? osl[p] : sl[p];
        s2v[p] = h ? sl[p] : osl[p];
        qv[p]  = h ? orn[p] : rn[p];
        kv[p]  = h ? rn[p] : orn[p];
    }

    // ---- softmax over j (duplicated on both lanes; cheap) ----
    float att[NBK][NBK];
    #pragma unroll
    for (int i = 0; i < NBK; ++i) {
        float dv[NBK];
        #pragma unroll
        for (int j = 0; j < NBK; ++j)
            dv[j] = (nm[i][j] + s1v[i] + s2v[j] + c0) *
                    __builtin_amdgcn_rcpf(fmaxf(qv[i] * kv[j], EPS));
        float mx = fmaxf(dv[0], fmaxf(dv[1], dv[2]));
        float e0 = __expf(dv[0] - mx);
        float e1 = __expf(dv[1] - mx);
        float e2 = __expf(dv[2] - mx);
        float inv = __builtin_amdgcn_rcpf(e0 + e1 + e2);
        att[i][0] = e0 * inv;
        att[i][1] = e1 * inv;
        att[i][2] = e2 * inv;
    }

    // ---- a_tilde + bf16 pack + LDS write: e-range split ----
    // h=0: e 0..11 -> dwords 0..5 (+ zero dwords 13..15)
    // h=1: e 12..23 -> dwords 6..11; e24+bias -> dword 12
    #pragma unroll
    for (int i = 0; i < NBK; ++i) {
        unsigned int* dst = (unsigned int*)&At[(le * 3 + i) * 40];
        #pragma unroll
        for (int d = 0; d < 6; ++d) {
            // e0 = h*12 + 2d, e1 = e0+1 ; runtime only through ba -> select
            float a_lo = ba[0 * BAD + 2 * d]     * att[i][0] + ba[1 * BAD + 2 * d]     * att[i][1] + ba[2 * BAD + 2 * d]     * att[i][2];
            float a_hi = ba[0 * BAD + 2 * d + 1] * att[i][0] + ba[1 * BAD + 2 * d + 1] * att[i][1] + ba[2 * BAD + 2 * d + 1] * att[i][2];
            float b_lo = ba[0 * BAD + 12 + 2 * d]     * att[i][0] + ba[1 * BAD + 12 + 2 * d]     * att[i][1] + ba[2 * BAD + 12 + 2 * d]     * att[i][2];
            float b_hi = ba[0 * BAD + 12 + 2 * d + 1] * att[i][0] + ba[1 * BAD + 12 + 2 * d + 1] * att[i][1] + ba[2 * BAD + 12 + 2 * d + 1] * att[i][2];
            float v_lo = h ? b_lo : a_lo;
            float v_hi = h ? b_hi : a_hi;
            dst[h * 6 + d] = (unsigned int)f2bf(v_lo) | ((unsigned int)f2bf(v_hi) << 16);
        }
        if (h) {
            float v24 = ba[0 * BAD + 24] * att[i][0] + ba[1 * BAD + 24] * att[i][1] + ba[2 * BAD + 24] * att[i][2];
            dst[12] = (unsigned int)f2bf(v24) | (0x3F80u << 16);
        } else {
            dst[13] = 0u; dst[14] = 0u; dst[15] = 0u;
        }
    }

    // At is wave-private: pair lanes and phase-2 tiles belong to the same wave.
    asm volatile("s_waitcnt lgkmcnt(0)" ::: "memory");

    // ================= phase 2: MFMA (6 tiles per wave) =================
    {
        int w = t >> 6;
        int m = lane & 15, q = lane >> 4;
        const short8* pkM = (const short8*)(ws + O_PKM);
        const short8* pkW2 = (const short8*)(ws + O_PKW2);
        float b2v = ws[O_B2 + m];
        long blockbase = (long)blockIdx.x * 128;
        int addrA = ((q & 1) ? (m + 32) : m) << 2;
        int addrB = addrA + 64;
        bool hiSel = (q >= 2);

        for (int tt = 0; tt < 6; ++tt) {
            int tile = w * 6 + tt;            // rows tile*16 .. +15 (0..383)
            short8 af = *(const short8*)&At[(tile * 16 + m) * 40 + q * 8];
            floatx4 accT[8];
            #pragma unroll
            for (int nt = 0; nt < 8; ++nt) {
                floatx4 z = {0.f, 0.f, 0.f, 0.f};
                accT[nt] = __builtin_amdgcn_mfma_f32_16x16x32_bf16(pkM[nt * 64 + lane], af, z, 0, 0, 0);
            }
            unsigned int pk[8][2];
            #pragma unroll
            for (int nt = 0; nt < 8; ++nt) {
                float x0 = fmaf(-2.0f, __builtin_amdgcn_rcpf(1.0f + __expf(accT[nt][0])), 1.0f);
                float x1 = fmaf(-2.0f, __builtin_amdgcn_rcpf(1.0f + __expf(accT[nt][1])), 1.0f);
                float x2 = fmaf(-2.0f, __builtin_amdgcn_rcpf(1.0f + __expf(accT[nt][2])), 1.0f);
                float x3 = fmaf(-2.0f, __builtin_amdgcn_rcpf(1.0f + __expf(accT[nt][3])), 1.0f);
                asm("v_cvt_pk_bf16_f32 %0, %1, %2" : "=v"(pk[nt][0]) : "v"(x0), "v"(x1));
                asm("v_cvt_pk_bf16_f32 %0, %1, %2" : "=v"(pk[nt][1]) : "v"(x2), "v"(x3));
            }
            floatx4 acc2 = {0.f, 0.f, 0.f, 0.f};
            #pragma unroll
            for (int kt = 0; kt < 4; ++kt) {
                int lo0 = __builtin_amdgcn_ds_bpermute(addrA, (int)pk[2 * kt][0]);
                int hi0 = __builtin_amdgcn_ds_bpermute(addrA, (int)pk[2 * kt + 1][0]);
                int lo1 = __builtin_amdgcn_ds_bpermute(addrA, (int)pk[2 * kt][1]);
                int hi1 = __builtin_amdgcn_ds_bpermute(addrA, (int)pk[2 * kt + 1][1]);
                int lo2 = __builtin_amdgcn_ds_bpermute(addrB, (int)pk[2 * kt][0]);
                int hi2 = __builtin_amdgcn_ds_bpermute(addrB, (int)pk[2 * kt + 1][0]);
                int lo3 = __builtin_amdgcn_ds_bpermute(addrB, (int)pk[2 * kt][1]);
                int hi3 = __builtin_amdgcn_ds_bpermute(addrB, (int)pk[2 * kt + 1][1]);
                union { unsigned int u[4]; short8 s; } a2u;
                a2u.u[0] = (unsigned int)(hiSel ? hi0 : lo0);
                a2u.u[1] = (unsigned int)(hiSel ? hi1 : lo1);
                a2u.u[2] = (unsigned int)(hiSel ? hi2 : lo2);
                a2u.u[3] = (unsigned int)(hiSel ? hi3 : lo3);
                acc2 = __builtin_amdgcn_mfma_f32_16x16x32_bf16(a2u.s, pkW2[kt * 64 + lane], acc2, 0, 0, 0);
            }
            #pragma unroll
            for (int rr = 0; rr < 4; ++rr) {
                int lrow = tile * 16 + q * 4 + rr;     // 0..383
                int et = lrow / 3, i = lrow - et * 3;
                long ge = blockbase + et;
                float base = states[ge * 48 + i * 16 + m];
                out[ge * OUTD + i * 16 + m] = acc2[rr] + base + b2v;
            }
        }
    }
}

extern "C" void kernel_launch(void* const* d_in, const int* in_sizes, int n_in,
                              void* d_out, int out_size, void* d_ws, size_t ws_size,
                              hipStream_t stream) {
    const float* states = (const float*)d_in[0];
    const float* action = (const float*)d_in[1];
    const int* block_id = (const int*)d_in[2];
    const float* Wq = (const float*)d_in[3];
    const float* bq = (const float*)d_in[4];
    const float* Wk = (const float*)d_in[5];
    const float* bk = (const float*)d_in[6];
    const float* Wv = (const float*)d_in[7];
    const float* bv = (const float*)d_in[8];
    const float* W1 = (const float*)d_in[9];
    const float* b1 = (const float*)d_in[10];
    const float* W2 = (const float*)d_in[11];
    const float* b2 = (const float*)d_in[12];
    const float* Wc1 = (const float*)d_in[13];
    const float* bc1 = (const float*)d_in[14];
    const float* Wc2 = (const float*)d_in[15];
    const float* bc2 = (const float*)d_in[16];
    float* out = (float*)d_out;
    float* ws = (float*)d_ws;

    hipLaunchKernelGGL(prep_dots, dim3((NDOT + 3) / 4), dim3(256), 0, stream,
                       Wq, bq, Wk, bk, Wv, bv, W1, b1, ws);
    hipLaunchKernelGGL(prep_copy, dim3((NCOPY + 255) / 256), dim3(256), 0, stream,
                       W2, b2, Wc1, bc1, Wc2, bc2, ws);
    hipLaunchKernelGGL(main_kernel, dim3(BTOT / 128), dim3(256), 0, stream,
                       states, action, block_id, ws, out);
}